// Round 4
// baseline (47.384 us; speedup 1.0000x reference)
//
#include <hip/hip_runtime.h>

// Problem constants (from reference): B=32, NY=32, NX=32, D=1024
#define PB 32
#define PNY 32
#define PNX 32
#define PD 1024
#define DCHUNK 256                 // floats per block along D (64 lanes * float4)
#define NCHUNK (PD / DCHUNK)       // 4

// One wave (64 threads) per (bp, d-chunk). Iterates source rows s=0..L-1
// (wave-uniform, monotone) with a 2-row register lookahead so each row's
// load is issued ~2 iterations before use. Each valid source row is loaded
// exactly once per block; outputs t are emitted while lo(t)==s.
__global__ __launch_bounds__(64) void upip_col_kernel(
    const float* __restrict__ x, const int* __restrict__ mask,
    float* __restrict__ out) {
    const int gb    = blockIdx.x;            // gb = bp * NCHUNK + chunk
    const int chunk = gb & (NCHUNK - 1);
    const int bp    = gb >> 2;               // / NCHUNK
    const int b     = bp >> 5;               // / NX
    const int xc    = bp & (PNX - 1);

    // Wave-level length: lanes 0..31 read mask[b, lane, xc]; popcount ballot.
    const int lane = threadIdx.x;            // 0..63
    int mv = 0;
    if (lane < PNY)
        mv = mask[(size_t)b * (PNY * PNX) + (size_t)lane * PNX + xc];
    const int   L  = (int)__popcll(__ballot(mv != 0));
    const float Lf = (float)L;

    // x layout: [B, NY, NX, D]; this thread's 16B slice of the column:
    const size_t row_stride = (size_t)PNX * PD;
    const float* colp = x + ((size_t)b * (PNY * PNX) + xc) * PD
                          + chunk * DCHUNK + lane * 4;
    float*       outp = out + (size_t)bp * PNY * PD + chunk * DCHUNK + lane * 4;

    const float scale = Lf * 0.03125f;       // L / 32, exact in fp32

    // Prologue: ra=row s, rb=row min(s+1,L-1), rc=row min(s+2,L-1) for s=0.
    float4 ra, rb, rc;
    ra = *reinterpret_cast<const float4*>(colp);
    rb = (L > 1) ? *reinterpret_cast<const float4*>(colp + row_stride) : ra;
    rc = (L > 2) ? *reinterpret_cast<const float4*>(colp + 2 * row_stride) : rb;

    int t = 0;
    for (int s = 0; s < L; ++s) {
        // Prefetch row s+3 (becomes rc for iteration s+1); wave-uniform.
        const bool need = (s + 3) <= (L - 1);
        float4 rd;
        if (need)
            rd = *reinterpret_cast<const float4*>(colp + (size_t)(s + 3) * row_stride);

        // Emit all outputs t with lo(t) == s, from resident ra (row s) and
        // rb (row min(s+1, L-1)). PyTorch align_corners=False, fp32 op-order.
        while (t < PNY) {
            float src = ((float)t + 0.5f) * scale - 0.5f;
            src = fminf(fmaxf(src, 0.0f), Lf - 1.0f);
            const int lo = (int)floorf(src);
            if (lo != s) break;
            const float w  = src - (float)lo;
            const float iw = 1.0f - w;
            float4 o;
            o.x = ra.x * iw + rb.x * w;
            o.y = ra.y * iw + rb.y * w;
            o.z = ra.z * iw + rb.z * w;
            o.w = ra.w * iw + rb.w * w;
            *reinterpret_cast<float4*>(outp + (size_t)t * PD) = o;
            ++t;
        }

        // Rotate: ra'=row s+1, rb'=row min(s+2,L-1), rc'=row min(s+3,L-1).
        ra = rb;
        rb = rc;
        if (need) rc = rd;
    }
}

extern "C" void kernel_launch(void* const* d_in, const int* in_sizes, int n_in,
                              void* d_out, int out_size, void* d_ws, size_t ws_size,
                              hipStream_t stream) {
    const float* x    = (const float*)d_in[0];
    const int*   mask = (const int*)d_in[1];
    float*       out  = (float*)d_out;

    const int nblocks = PB * PNX * NCHUNK;   // 4096 single-wave blocks
    upip_col_kernel<<<nblocks, 64, 0, stream>>>(x, mask, out);
}

// Round 5
// 43.229 us; speedup vs baseline: 1.0961x; 1.0961x over previous
//
#include <hip/hip_runtime.h>

// Problem constants (from reference): B=32, NY=32, NX=32, D=1024
#define PB 32
#define PNY 32
#define PNX 32
#define PD 1024
#define DCHUNK 256                 // floats per wave along D (64 lanes * float4)
#define NCHUNK (PD / DCHUNK)       // 4
#define THALF 16                   // t's per wave (NY/2)

// 256-thread blocks, 4 waves each. Each wave owns (bp, d-chunk, t-half):
// walks its 16 output t's for a 256-float slice of one (b, xc) column.
// lo(t) is monotone nondecreasing with step <= 1, so a 2-register rolling
// cache loads each needed source row exactly once per wave.
// 8192 waves total -> ~32 waves/CU resident (vs 16 with single-wave WGs).
__global__ __launch_bounds__(256) void upip_col_kernel(
    const float* __restrict__ x, const int* __restrict__ mask,
    float* __restrict__ out) {
    const int wid   = (blockIdx.x << 2) | (threadIdx.x >> 6);  // global wave id
    const int thalf = wid & 1;               // 0: t=0..15, 1: t=16..31
    const int gb    = wid >> 1;              // gb = bp * NCHUNK + chunk
    const int chunk = gb & (NCHUNK - 1);
    const int bp    = gb >> 2;               // / NCHUNK
    const int b     = bp >> 5;               // / NX
    const int xc    = bp & (PNX - 1);

    // Wave-level length: lanes 0..31 read mask[b, lane, xc]; popcount ballot.
    const int lane = threadIdx.x & 63;
    int mv = 0;
    if (lane < PNY)
        mv = mask[(size_t)b * (PNY * PNX) + (size_t)lane * PNX + xc];
    const int   L  = (int)__popcll(__ballot(mv != 0));
    const float Lf = (float)L;

    // x layout: [B, NY, NX, D]; this thread's 16B slice of the column:
    const size_t row_stride = (size_t)PNX * PD;
    const float* colp = x + ((size_t)b * (PNY * PNX) + xc) * PD
                          + chunk * DCHUNK + (lane << 2);
    float*       outp = out + (size_t)bp * PNY * PD + chunk * DCHUNK + (lane << 2);

    const float scale = Lf * 0.03125f;       // L / 32, exact in fp32

    int    c0 = -1, c1 = -1;                 // cached row indices for r0, r1
    float4 r0, r1;

    const int t0 = thalf << 4;               // 0 or 16
#pragma unroll
    for (int i = 0; i < THALF; ++i) {
        const int t = t0 + i;
        // PyTorch F.interpolate(linear, align_corners=False), fp32 op-order
        float src = ((float)t + 0.5f) * scale - 0.5f;
        src = fminf(fmaxf(src, 0.0f), Lf - 1.0f);
        const int   lo = (int)floorf(src);
        const int   hi = min(lo + 1, L - 1);
        const float w  = src - (float)lo;

        // Rolling 2-row cache; all branches are wave-uniform.
        if (lo == c1)      { r0 = r1; c0 = c1; }
        else if (lo != c0) { r0 = *reinterpret_cast<const float4*>(
                                 colp + (size_t)lo * row_stride); c0 = lo; }
        if (hi == c0)      { r1 = r0; c1 = c0; }
        else if (hi != c1) { r1 = *reinterpret_cast<const float4*>(
                                 colp + (size_t)hi * row_stride); c1 = hi; }

        const float iw = 1.0f - w;
        float4 o;
        o.x = r0.x * iw + r1.x * w;
        o.y = r0.y * iw + r1.y * w;
        o.z = r0.z * iw + r1.z * w;
        o.w = r0.w * iw + r1.w * w;
        *reinterpret_cast<float4*>(outp + (size_t)t * PD) = o;
    }
}

extern "C" void kernel_launch(void* const* d_in, const int* in_sizes, int n_in,
                              void* d_out, int out_size, void* d_ws, size_t ws_size,
                              hipStream_t stream) {
    const float* x    = (const float*)d_in[0];
    const int*   mask = (const int*)d_in[1];
    float*       out  = (float*)d_out;

    const int nwaves  = PB * PNX * NCHUNK * 2;  // 8192 waves
    const int nblocks = nwaves / 4;             // 2048 blocks of 256 threads
    upip_col_kernel<<<nblocks, 256, 0, stream>>>(x, mask, out);
}

// Round 7
// 38.951 us; speedup vs baseline: 1.2165x; 1.1098x over previous
//
#include <hip/hip_runtime.h>

// Problem constants (from reference): B=32, NY=32, NX=32, D=1024
#define PB 32
#define PNY 32
#define PNX 32
#define PD 1024
#define DCHUNK 256                 // floats per block along D (64 lanes * float4)
#define NCHUNK (PD / DCHUNK)       // 4

typedef float fvec4 __attribute__((ext_vector_type(4)));  // clang-native vec

// One wave (64 threads) per (bp, d-chunk). Walks all 32 output t's for its
// 256-float slice of one (b, xc) column. Branch-free body: lo/hi rows are
// loaded unconditionally each iteration (addresses depend only on scalar L),
// so the fully-unrolled loop has NO inter-iteration dependencies and the
// compiler can cluster/pipeline the loads. Within-wave repeat loads of the
// same row hit L1 (2 KB live set) -> HBM traffic stays minimal.
__global__ __launch_bounds__(64) void upip_col_kernel(
    const float* __restrict__ x, const int* __restrict__ mask,
    float* __restrict__ out) {
    const int gb    = blockIdx.x;            // gb = bp * NCHUNK + chunk
    const int chunk = gb & (NCHUNK - 1);
    const int bp    = gb >> 2;               // / NCHUNK
    const int b     = bp >> 5;               // / NX
    const int xc    = bp & (PNX - 1);

    // Wave-level length: lanes 0..31 read mask[b, lane, xc]; popcount ballot.
    const int lane = threadIdx.x;            // 0..63
    int mv = 0;
    if (lane < PNY)
        mv = mask[(size_t)b * (PNY * PNX) + (size_t)lane * PNX + xc];
    const int   L  = (int)__popcll(__ballot(mv != 0));
    const float Lf = (float)L;

    // x layout: [B, NY, NX, D]; this thread's 16B slice of the column:
    const size_t row_stride = (size_t)PNX * PD;
    const float* colp = x + ((size_t)b * (PNY * PNX) + xc) * PD
                          + chunk * DCHUNK + (lane << 2);
    float*       outp = out + (size_t)bp * PNY * PD + chunk * DCHUNK + (lane << 2);

    const float scale = Lf * 0.03125f;       // L / 32, exact in fp32

#pragma unroll
    for (int t = 0; t < PNY; ++t) {
        // PyTorch F.interpolate(linear, align_corners=False), fp32 op-order
        float src = ((float)t + 0.5f) * scale - 0.5f;
        src = fminf(fmaxf(src, 0.0f), Lf - 1.0f);
        const int   lo = (int)floorf(src);
        const int   hi = min(lo + 1, L - 1);
        const float w  = src - (float)lo;

        const fvec4 r0 = *reinterpret_cast<const fvec4*>(
            colp + (size_t)lo * row_stride);
        const fvec4 r1 = *reinterpret_cast<const fvec4*>(
            colp + (size_t)hi * row_stride);

        const float iw = 1.0f - w;
        fvec4 o = r0 * iw + r1 * w;
        __builtin_nontemporal_store(o, reinterpret_cast<fvec4*>(
            outp + (size_t)t * PD));
    }
}

extern "C" void kernel_launch(void* const* d_in, const int* in_sizes, int n_in,
                              void* d_out, int out_size, void* d_ws, size_t ws_size,
                              hipStream_t stream) {
    const float* x    = (const float*)d_in[0];
    const int*   mask = (const int*)d_in[1];
    float*       out  = (float*)d_out;

    const int nblocks = PB * PNX * NCHUNK;   // 4096 single-wave blocks
    upip_col_kernel<<<nblocks, 64, 0, stream>>>(x, mask, out);
}